// Round 2
// 390.679 us; speedup vs baseline: 1.1194x; 1.1194x over previous
//
#include <hip/hip_runtime.h>
#include <math.h>

#define C_CLS 4
#define D_HALF 512
#define D4 128      // D_HALF / 4
#define DFEAT 1024
#define BB 32

typedef float f4 __attribute__((ext_vector_type(4)));

// ---------------------------------------------------------------------------
// Kernel A: fused masked segmented sums over enc (B*SE blocks) + pred
// (B*SP blocks), 1-D grid, block 256. tx = float4 column (0..127), ty = t
// parity. partial layout: [B][splits][C_CLS][D_HALF] floats.
// Block 0 also zeroes out[0] (kernel B accumulates the loss there with
// atomics; ordering guaranteed by the A->B launch dependency).
// Nontemporal loads: the 335 MB stream is read exactly once.
// 4-deep load pipeline: 4 independent 1 KB/wave loads in flight before the
// dependent FMAs.
// ---------------------------------------------------------------------------
__global__ void masked_sum_fused(const float* __restrict__ enc, const float* __restrict__ pred,
                                 const int* __restrict__ fl, const int* __restrict__ ftl,
                                 float* __restrict__ enc_part, float* __restrict__ pred_part,
                                 float* __restrict__ out,
                                 int T, int U, int SE, int SP) {
    int bid = blockIdx.x;
    if (bid == 0 && threadIdx.x == 0) out[0] = 0.0f;

    const float* x; const int* labels; float* partial;
    int Tlen, splits, b, s;
    if (bid < BB * SE) {
        x = enc; labels = fl; partial = enc_part; Tlen = T; splits = SE;
        b = bid / SE; s = bid - b * SE;
    } else {
        int idx = bid - BB * SE;
        x = pred; labels = ftl; partial = pred_part; Tlen = U; splits = SP;
        b = idx / SP; s = idx - b * SP;
    }
    int len = Tlen / splits;          // pow2/pow2 -> exact; len in {64..128}
    int t0 = s * len;
    int tx = threadIdx.x & 127;
    int ty = threadIdx.x >> 7;

    __shared__ int lab[256];
    const int* labg = labels + (size_t)b * Tlen + t0;
    for (int i = threadIdx.x; i < len; i += 256) lab[i] = labg[i];
    __syncthreads();

    const f4* x4 = (const f4*)x + ((size_t)b * Tlen + t0) * D4 + tx;
    f4 acc[C_CLS];
#pragma unroll
    for (int k = 0; k < C_CLS; k++) acc[k] = (f4){0.f, 0.f, 0.f, 0.f};

    // t-loop, parity-split across ty, 4-deep unroll: four 1 KB/wave loads in
    // flight before the dependent FMAs. Class is wave-uniform (t uniform per
    // wave) so the (c==k) select compiles to SALU + sgpr-operand FMA.
    int t = ty;
    for (; t + 6 < len; t += 8) {
        f4 v0 = __builtin_nontemporal_load(&x4[(size_t)t * D4]);
        f4 v1 = __builtin_nontemporal_load(&x4[(size_t)(t + 2) * D4]);
        f4 v2 = __builtin_nontemporal_load(&x4[(size_t)(t + 4) * D4]);
        f4 v3 = __builtin_nontemporal_load(&x4[(size_t)(t + 6) * D4]);
        int c0 = lab[t], c1 = lab[t + 2], c2 = lab[t + 4], c3 = lab[t + 6];
#pragma unroll
        for (int k = 0; k < C_CLS; k++) {
            acc[k] += v0 * (float)(c0 == k);
            acc[k] += v1 * (float)(c1 == k);
            acc[k] += v2 * (float)(c2 == k);
            acc[k] += v3 * (float)(c3 == k);
        }
    }
    for (; t < len; t += 2) {
        f4 v = __builtin_nontemporal_load(&x4[(size_t)t * D4]);
        int c = lab[t];
#pragma unroll
        for (int k = 0; k < C_CLS; k++) acc[k] += v * (float)(c == k);
    }

    __shared__ f4 cbuf[C_CLS][D4];
    if (ty == 1) {
#pragma unroll
        for (int k = 0; k < C_CLS; k++) cbuf[k][tx] = acc[k];
    }
    __syncthreads();
    if (ty == 0) {
        f4* o4 = (f4*)partial + (size_t)(b * splits + s) * C_CLS * D4 + tx;
#pragma unroll
        for (int k = 0; k < C_CLS; k++)
            o4[(size_t)k * D4] = acc[k] + cbuf[k][tx];
    }
}

// ---------------------------------------------------------------------------
// Block-wide reductions over 512 threads (8 waves). Wave shuffle reduce, one
// LDS bounce, result broadcast to all threads. Each variant has its own LDS.
// ---------------------------------------------------------------------------
__device__ __forceinline__ float blockReduceSum512(float v) {
    __shared__ float red[8];
#pragma unroll
    for (int off = 32; off; off >>= 1) v += __shfl_down(v, off);
    int wid = threadIdx.x >> 6;
    __syncthreads();
    if ((threadIdx.x & 63) == 0) red[wid] = v;
    __syncthreads();
    float s = 0.f;
#pragma unroll
    for (int i = 0; i < 8; i++) s += red[i];
    return s;
}

__device__ __forceinline__ void blockReduce2_512(float& a, float& b) {
    __shared__ float red2[8][2];
#pragma unroll
    for (int off = 32; off; off >>= 1) {
        a += __shfl_down(a, off);
        b += __shfl_down(b, off);
    }
    int wid = threadIdx.x >> 6;
    __syncthreads();
    if ((threadIdx.x & 63) == 0) { red2[wid][0] = a; red2[wid][1] = b; }
    __syncthreads();
    float sa = 0.f, sb = 0.f;
#pragma unroll
    for (int i = 0; i < 8; i++) { sa += red2[i][0]; sb += red2[i][1]; }
    a = sa; b = sb;
}

__device__ __forceinline__ void blockReduce4_512(float* p) {
    __shared__ float red4[8][4];
#pragma unroll
    for (int off = 32; off; off >>= 1) {
#pragma unroll
        for (int n = 0; n < 4; n++) p[n] += __shfl_down(p[n], off);
    }
    int wid = threadIdx.x >> 6;
    __syncthreads();
    if ((threadIdx.x & 63) == 0) {
#pragma unroll
        for (int n = 0; n < 4; n++) red4[wid][n] = p[n];
    }
    __syncthreads();
#pragma unroll
    for (int n = 0; n < 4; n++) {
        float s = 0.f;
#pragma unroll
        for (int i = 0; i < 8; i++) s += red4[i][n];
        p[n] = s;
    }
}

// ---------------------------------------------------------------------------
// Kernel B: per-(b,c) row, 512 threads. Thread d owns feat dims d and 512+d
// ENTIRELY IN REGISTERS (no feat LDS array, no re-read passes):
//   counts (packed exact-int float reduce) -> split reduce (4-way unrolled,
//   independent accumulators) -> mean -> one-pass sum/sumsq LN stats ->
//   LN + 4-logit matvec from registers -> log_softmax diag -> atomicAdd loss.
// grid (B, C_CLS), block 512. 6 barriers total (was ~16 at 256 threads).
// ---------------------------------------------------------------------------
__global__ __launch_bounds__(512)
void finalize_loss_kernel(const float* __restrict__ enc_part,
                          const float* __restrict__ pred_part,
                          const int* __restrict__ fl, const int* __restrict__ ftl,
                          const int* __restrict__ label,
                          const float* __restrict__ norm_w, const float* __restrict__ norm_b,
                          const float* __restrict__ head_w, const float* __restrict__ head_b,
                          float* __restrict__ out,
                          int T, int U, int B, int SE, int SP) {
    int b = blockIdx.x;
    int c = blockIdx.y;
    int d = threadIdx.x;              // 0..511 == feat dim within each half

    // --- packed label counts: ce in bits [0,13), cp<<13. Totals < 2^24 so the
    // float reduce is exact. Issued first so these loads overlap everything.
    int pk = 0;
    {
        const int* p = fl + (size_t)b * T;
        for (int i = d; i < T; i += 512) pk += (p[i] == c);
        const int* q = ftl + (size_t)b * U;
        for (int i = d; i < U; i += 512) pk += (q[i] == c) << 13;
    }

    // --- split reduction, 4 independent accumulators (loads pipeline freely;
    // no barrier until the count reduce below).
    const int estr = C_CLS * D_HALF;
    float e0 = 0.f, e1 = 0.f, e2 = 0.f, e3 = 0.f;
    {
        const float* ep = enc_part + ((size_t)b * SE * C_CLS + c) * D_HALF + d;
        for (int sp = 0; sp < SE; sp += 4) {
            e0 += ep[(size_t)(sp + 0) * estr];
            e1 += ep[(size_t)(sp + 1) * estr];
            e2 += ep[(size_t)(sp + 2) * estr];
            e3 += ep[(size_t)(sp + 3) * estr];
        }
    }
    float esum = (e0 + e1) + (e2 + e3);
    float p0 = 0.f, p1 = 0.f, p2 = 0.f, p3 = 0.f;
    {
        const float* pp = pred_part + ((size_t)b * SP * C_CLS + c) * D_HALF + d;
        for (int sp = 0; sp < SP; sp += 4) {
            p0 += pp[(size_t)(sp + 0) * estr];
            p1 += pp[(size_t)(sp + 1) * estr];
            p2 += pp[(size_t)(sp + 2) * estr];
            p3 += pp[(size_t)(sp + 3) * estr];
        }
    }
    float psum = (p0 + p1) + (p2 + p3);

    int cpk = (int)blockReduceSum512((float)pk);
    float cnt_e = fmaxf((float)(cpk & 8191), 1.0f);
    float cnt_p = fmaxf((float)(cpk >> 13), 1.0f);

    float fe = esum / cnt_e;          // feat[d]
    float fp = psum / cnt_p;          // feat[512+d]

    // --- one-pass LN stats: var = E[x^2] - mu^2 (values ~0.05, exact enough)
    float lsum = fe + fp;
    float lsq  = fe * fe + fp * fp;
    blockReduce2_512(lsum, lsq);
    float mu   = lsum * (1.0f / DFEAT);
    float var  = lsq * (1.0f / DFEAT) - mu * mu;
    float rstd = rsqrtf(var + 1e-5f);

    // --- LN + head matvec straight from registers
    float fn0 = (fe - mu) * rstd * norm_w[d] + norm_b[d];
    float fn1 = (fp - mu) * rstd * norm_w[D_HALF + d] + norm_b[D_HALF + d];
    float part[C_CLS];
#pragma unroll
    for (int n = 0; n < C_CLS; n++)
        part[n] = fn0 * head_w[(size_t)n * DFEAT + d]
                + fn1 * head_w[(size_t)n * DFEAT + D_HALF + d];
    blockReduce4_512(part);

    if (threadIdx.x == 0) {
        float logits[C_CLS];
#pragma unroll
        for (int n = 0; n < C_CLS; n++) logits[n] = part[n] + head_b[n];
        float m = fmaxf(fmaxf(logits[0], logits[1]), fmaxf(logits[2], logits[3]));
        float se = 0.f;
#pragma unroll
        for (int n = 0; n < C_CLS; n++) se += expf(logits[n] - m);
        float lp = logits[c] - (m + logf(se));   // logp[b,c,c]
        int occ = 0;
#pragma unroll
        for (int l = 0; l < C_CLS; l++) occ += (label[b * C_CLS + l] == c);
        if (occ)
            atomicAdd(out, -lp * (float)occ * (1.0f / (BB * C_CLS)));
    }
}

// ---------------------------------------------------------------------------
extern "C" void kernel_launch(void* const* d_in, const int* in_sizes, int n_in,
                              void* d_out, int out_size, void* d_ws, size_t ws_size,
                              hipStream_t stream) {
    const float* enc_out      = (const float*)d_in[0];
    const float* pred_out     = (const float*)d_in[1];
    const int*   frame_label  = (const int*)d_in[2];
    const int*   frame_tlabel = (const int*)d_in[3];
    const int*   label        = (const int*)d_in[4];
    const float* norm_w       = (const float*)d_in[5];
    const float* norm_b       = (const float*)d_in[6];
    const float* head_w       = (const float*)d_in[7];
    const float* head_b       = (const float*)d_in[8];
    float* out = (float*)d_out;

    const int B = BB, T = 4096, U = 1024;
    int SE = 32, SP = 16;     // 1024 + 512 blocks; partials = 12.6 MB
    auto need = [&](int se, int sp) -> size_t {
        return ((size_t)B * se * C_CLS * D_HALF + (size_t)B * sp * C_CLS * D_HALF)
               * sizeof(float);
    };
    while (need(SE, SP) > ws_size && SE > 16) { SE >>= 1; if (SP > 4) SP >>= 1; }

    float* enc_part  = (float*)d_ws;
    float* pred_part = enc_part + (size_t)B * SE * C_CLS * D_HALF;

    masked_sum_fused<<<B * SE + B * SP, 256, 0, stream>>>(enc_out, pred_out,
                                                          frame_label, frame_tlabel,
                                                          enc_part, pred_part, out,
                                                          T, U, SE, SP);
    finalize_loss_kernel<<<dim3(B, C_CLS), 512, 0, stream>>>(enc_part, pred_part,
                                                             frame_label, frame_tlabel, label,
                                                             norm_w, norm_b, head_w, head_b,
                                                             out, T, U, B, SE, SP);
}

// Round 3
// 385.338 us; speedup vs baseline: 1.1349x; 1.0139x over previous
//
#include <hip/hip_runtime.h>
#include <math.h>

#define C_CLS 4
#define D_HALF 512
#define D4 128      // D_HALF / 4
#define DFEAT 1024
#define BB 32

typedef float f4 __attribute__((ext_vector_type(4)));

// ---------------------------------------------------------------------------
// Kernel A: fused masked segmented sums over enc (B*SE blocks) + pred
// (B*SP blocks), 1-D grid, block 256. tx = float4 column (0..127), ty = t
// parity. partial layout: [B][splits][C_CLS][D_HALF] floats.
// NEW: also emits per-split per-class label counts (from the lab[] LDS copy,
// via 4-counter LDS atomics) so kernel B never rescans the label streams.
// Block 0 also zeroes out[0] (kernel B accumulates the loss there with
// atomics; ordering guaranteed by the A->B launch dependency).
// Nontemporal loads: the 335 MB stream is read exactly once.
// ---------------------------------------------------------------------------
__global__ void masked_sum_fused(const float* __restrict__ enc, const float* __restrict__ pred,
                                 const int* __restrict__ fl, const int* __restrict__ ftl,
                                 float* __restrict__ enc_part, float* __restrict__ pred_part,
                                 int* __restrict__ enc_cnt, int* __restrict__ pred_cnt,
                                 float* __restrict__ out,
                                 int T, int U, int SE, int SP) {
    int bid = blockIdx.x;
    if (bid == 0 && threadIdx.x == 0) out[0] = 0.0f;

    const float* x; const int* labels; float* partial; int* cnt;
    int Tlen, splits, b, s;
    if (bid < BB * SE) {
        x = enc; labels = fl; partial = enc_part; cnt = enc_cnt;
        Tlen = T; splits = SE;
        b = bid / SE; s = bid - b * SE;
    } else {
        int idx = bid - BB * SE;
        x = pred; labels = ftl; partial = pred_part; cnt = pred_cnt;
        Tlen = U; splits = SP;
        b = idx / SP; s = idx - b * SP;
    }
    int len = Tlen / splits;          // pow2/pow2 -> exact; len in {128,256}
    int t0 = s * len;
    int tx = threadIdx.x & 127;
    int ty = threadIdx.x >> 7;

    __shared__ int lab[256];
    __shared__ int scnt[C_CLS];
    if (threadIdx.x < C_CLS) scnt[threadIdx.x] = 0;
    const int* labg = labels + (size_t)b * Tlen + t0;
    for (int i = threadIdx.x; i < len; i += 256) lab[i] = labg[i];
    __syncthreads();

    // per-slice class counts (len <= 256, one element per thread)
    if (threadIdx.x < len) atomicAdd(&scnt[lab[threadIdx.x]], 1);

    const f4* x4 = (const f4*)x + ((size_t)b * Tlen + t0) * D4 + tx;
    f4 acc[C_CLS];
#pragma unroll
    for (int k = 0; k < C_CLS; k++) acc[k] = (f4){0.f, 0.f, 0.f, 0.f};

    // t-loop, parity-split across ty, 4-deep unroll: four 1 KB/wave loads in
    // flight before the dependent FMAs. Class is wave-uniform (t uniform per
    // wave) so the (c==k) select compiles to SALU + sgpr-operand FMA.
    int t = ty;
    for (; t + 6 < len; t += 8) {
        f4 v0 = __builtin_nontemporal_load(&x4[(size_t)t * D4]);
        f4 v1 = __builtin_nontemporal_load(&x4[(size_t)(t + 2) * D4]);
        f4 v2 = __builtin_nontemporal_load(&x4[(size_t)(t + 4) * D4]);
        f4 v3 = __builtin_nontemporal_load(&x4[(size_t)(t + 6) * D4]);
        int c0 = lab[t], c1 = lab[t + 2], c2 = lab[t + 4], c3 = lab[t + 6];
#pragma unroll
        for (int k = 0; k < C_CLS; k++) {
            acc[k] += v0 * (float)(c0 == k);
            acc[k] += v1 * (float)(c1 == k);
            acc[k] += v2 * (float)(c2 == k);
            acc[k] += v3 * (float)(c3 == k);
        }
    }
    for (; t < len; t += 2) {
        f4 v = __builtin_nontemporal_load(&x4[(size_t)t * D4]);
        int c = lab[t];
#pragma unroll
        for (int k = 0; k < C_CLS; k++) acc[k] += v * (float)(c == k);
    }

    __shared__ f4 cbuf[C_CLS][D4];
    if (ty == 1) {
#pragma unroll
        for (int k = 0; k < C_CLS; k++) cbuf[k][tx] = acc[k];
    }
    __syncthreads();                  // also makes scnt atomics visible
    if (ty == 0) {
        f4* o4 = (f4*)partial + (size_t)(b * splits + s) * C_CLS * D4 + tx;
#pragma unroll
        for (int k = 0; k < C_CLS; k++)
            o4[(size_t)k * D4] = acc[k] + cbuf[k][tx];
    }
    if (threadIdx.x < C_CLS)
        cnt[(size_t)(b * splits + s) * C_CLS + threadIdx.x] = scnt[threadIdx.x];
}

// ---------------------------------------------------------------------------
// Block-wide reductions over 512 threads (8 waves). Wave shuffle reduce, one
// LDS bounce, result broadcast to all threads. Each variant has its own LDS.
// ---------------------------------------------------------------------------
__device__ __forceinline__ float blockReduceSum512(float v) {
    __shared__ float red[8];
#pragma unroll
    for (int off = 32; off; off >>= 1) v += __shfl_down(v, off);
    int wid = threadIdx.x >> 6;
    __syncthreads();
    if ((threadIdx.x & 63) == 0) red[wid] = v;
    __syncthreads();
    float s = 0.f;
#pragma unroll
    for (int i = 0; i < 8; i++) s += red[i];
    return s;
}

__device__ __forceinline__ void blockReduce2_512(float& a, float& b) {
    __shared__ float red2[8][2];
#pragma unroll
    for (int off = 32; off; off >>= 1) {
        a += __shfl_down(a, off);
        b += __shfl_down(b, off);
    }
    int wid = threadIdx.x >> 6;
    __syncthreads();
    if ((threadIdx.x & 63) == 0) { red2[wid][0] = a; red2[wid][1] = b; }
    __syncthreads();
    float sa = 0.f, sb = 0.f;
#pragma unroll
    for (int i = 0; i < 8; i++) { sa += red2[i][0]; sb += red2[i][1]; }
    a = sa; b = sb;
}

__device__ __forceinline__ void blockReduce4_512(float* p) {
    __shared__ float red4[8][4];
#pragma unroll
    for (int off = 32; off; off >>= 1) {
#pragma unroll
        for (int n = 0; n < 4; n++) p[n] += __shfl_down(p[n], off);
    }
    int wid = threadIdx.x >> 6;
    __syncthreads();
    if ((threadIdx.x & 63) == 0) {
#pragma unroll
        for (int n = 0; n < 4; n++) red4[wid][n] = p[n];
    }
    __syncthreads();
#pragma unroll
    for (int n = 0; n < 4; n++) {
        float s = 0.f;
#pragma unroll
        for (int i = 0; i < 8; i++) s += red4[i][n];
        p[n] = s;
    }
}

// ---------------------------------------------------------------------------
// Kernel B: per-(b,c) row, 512 threads. Thread d owns feat dims d and 512+d
// ENTIRELY IN REGISTERS. Counts come from kernel A's per-split count arrays
// (24 scalar loads) instead of rescanning the 5120-int label rows.
//   packed exact-int count reduce -> split reduce (4-way unrolled) -> mean ->
//   one-pass sum/sumsq LN stats -> LN + 4-logit matvec -> log_softmax diag ->
//   atomicAdd loss. grid (B, C_CLS), block 512.
// ---------------------------------------------------------------------------
__global__ __launch_bounds__(512)
void finalize_loss_kernel(const float* __restrict__ enc_part,
                          const float* __restrict__ pred_part,
                          const int* __restrict__ enc_cnt, const int* __restrict__ pred_cnt,
                          const int* __restrict__ label,
                          const float* __restrict__ norm_w, const float* __restrict__ norm_b,
                          const float* __restrict__ head_w, const float* __restrict__ head_b,
                          float* __restrict__ out,
                          int B, int SE, int SP) {
    int b = blockIdx.x;
    int c = blockIdx.y;
    int d = threadIdx.x;              // 0..511 == feat dim within each half

    // --- packed label counts from A's count arrays: ce in bits [0,13),
    // cp<<13. Totals < 2^24 so the float reduce is exact.
    int pk = 0;
    if (d < SE)                 pk  = enc_cnt[(size_t)(b * SE + d) * C_CLS + c];
    int dp = d - 256;
    if (dp >= 0 && dp < SP)     pk += pred_cnt[(size_t)(b * SP + dp) * C_CLS + c] << 13;

    // --- split reduction, 4 independent accumulators (loads pipeline freely;
    // no barrier until the count reduce below).
    const int estr = C_CLS * D_HALF;
    float e0 = 0.f, e1 = 0.f, e2 = 0.f, e3 = 0.f;
    {
        const float* ep = enc_part + ((size_t)b * SE * C_CLS + c) * D_HALF + d;
        for (int sp = 0; sp < SE; sp += 4) {
            e0 += ep[(size_t)(sp + 0) * estr];
            e1 += ep[(size_t)(sp + 1) * estr];
            e2 += ep[(size_t)(sp + 2) * estr];
            e3 += ep[(size_t)(sp + 3) * estr];
        }
    }
    float esum = (e0 + e1) + (e2 + e3);
    float p0 = 0.f, p1 = 0.f, p2 = 0.f, p3 = 0.f;
    {
        const float* pp = pred_part + ((size_t)b * SP * C_CLS + c) * D_HALF + d;
        for (int sp = 0; sp < SP; sp += 4) {
            p0 += pp[(size_t)(sp + 0) * estr];
            p1 += pp[(size_t)(sp + 1) * estr];
            p2 += pp[(size_t)(sp + 2) * estr];
            p3 += pp[(size_t)(sp + 3) * estr];
        }
    }
    float psum = (p0 + p1) + (p2 + p3);

    int cpk = (int)blockReduceSum512((float)pk);
    float cnt_e = fmaxf((float)(cpk & 8191), 1.0f);
    float cnt_p = fmaxf((float)(cpk >> 13), 1.0f);

    float fe = esum / cnt_e;          // feat[d]
    float fp = psum / cnt_p;          // feat[512+d]

    // --- one-pass LN stats: var = E[x^2] - mu^2
    float lsum = fe + fp;
    float lsq  = fe * fe + fp * fp;
    blockReduce2_512(lsum, lsq);
    float mu   = lsum * (1.0f / DFEAT);
    float var  = lsq * (1.0f / DFEAT) - mu * mu;
    float rstd = rsqrtf(var + 1e-5f);

    // --- LN + head matvec straight from registers
    float fn0 = (fe - mu) * rstd * norm_w[d] + norm_b[d];
    float fn1 = (fp - mu) * rstd * norm_w[D_HALF + d] + norm_b[D_HALF + d];
    float part[C_CLS];
#pragma unroll
    for (int n = 0; n < C_CLS; n++)
        part[n] = fn0 * head_w[(size_t)n * DFEAT + d]
                + fn1 * head_w[(size_t)n * DFEAT + D_HALF + d];
    blockReduce4_512(part);

    if (threadIdx.x == 0) {
        float logits[C_CLS];
#pragma unroll
        for (int n = 0; n < C_CLS; n++) logits[n] = part[n] + head_b[n];
        float m = fmaxf(fmaxf(logits[0], logits[1]), fmaxf(logits[2], logits[3]));
        float se = 0.f;
#pragma unroll
        for (int n = 0; n < C_CLS; n++) se += expf(logits[n] - m);
        float lp = logits[c] - (m + logf(se));   // logp[b,c,c]
        int occ = 0;
#pragma unroll
        for (int l = 0; l < C_CLS; l++) occ += (label[b * C_CLS + l] == c);
        if (occ)
            atomicAdd(out, -lp * (float)occ * (1.0f / (BB * C_CLS)));
    }
}

// ---------------------------------------------------------------------------
extern "C" void kernel_launch(void* const* d_in, const int* in_sizes, int n_in,
                              void* d_out, int out_size, void* d_ws, size_t ws_size,
                              hipStream_t stream) {
    const float* enc_out      = (const float*)d_in[0];
    const float* pred_out     = (const float*)d_in[1];
    const int*   frame_label  = (const int*)d_in[2];
    const int*   frame_tlabel = (const int*)d_in[3];
    const int*   label        = (const int*)d_in[4];
    const float* norm_w       = (const float*)d_in[5];
    const float* norm_b       = (const float*)d_in[6];
    const float* head_w       = (const float*)d_in[7];
    const float* head_b       = (const float*)d_in[8];
    float* out = (float*)d_out;

    const int B = BB, T = 4096, U = 1024;
    int SE = 16, SP = 8;      // 512 + 256 blocks; partials = 6.3 MB
    auto need = [&](int se, int sp) -> size_t {
        return ((size_t)B * se * C_CLS * D_HALF + (size_t)B * sp * C_CLS * D_HALF)
               * sizeof(float)
             + ((size_t)B * se * C_CLS + (size_t)B * sp * C_CLS) * sizeof(int);
    };
    while (need(SE, SP) > ws_size && SE > 4) { SE >>= 1; if (SP > 4) SP >>= 1; }

    float* enc_part  = (float*)d_ws;
    float* pred_part = enc_part + (size_t)B * SE * C_CLS * D_HALF;
    int*   enc_cnt   = (int*)(pred_part + (size_t)B * SP * C_CLS * D_HALF);
    int*   pred_cnt  = enc_cnt + (size_t)B * SE * C_CLS;

    masked_sum_fused<<<B * SE + B * SP, 256, 0, stream>>>(enc_out, pred_out,
                                                          frame_label, frame_tlabel,
                                                          enc_part, pred_part,
                                                          enc_cnt, pred_cnt, out,
                                                          T, U, SE, SP);
    finalize_loss_kernel<<<dim3(B, C_CLS), 512, 0, stream>>>(enc_part, pred_part,
                                                             enc_cnt, pred_cnt, label,
                                                             norm_w, norm_b, head_w, head_b,
                                                             out, B, SE, SP);
}